// Round 2
// baseline (2057.514 us; speedup 1.0000x reference)
//
#include <hip/hip_runtime.h>

#define NN 100000
#define NETY 3
#define EE 200000
#define DH 128

// ---------------- count in-degree per (etype, dst) ----------------
__global__ void count_kernel(const int* __restrict__ dst, float* __restrict__ cnt) {
    int tid = blockIdx.x * blockDim.x + threadIdx.x;
    if (tid >= NETY * EE) return;
    int e = tid / EE;
    atomicAdd(&cnt[e * NN + dst[tid]], 1.0f);
}

// ---------------- scatter-add feat[src] into agg[dst] ----------------
// one thread per (edge, 4-float chunk); optional fused leaky_relu on load
template <int D, bool LRELU>
__global__ void aggregate_kernel(const float* __restrict__ feat,
                                 const int* __restrict__ src,
                                 const int* __restrict__ dst,
                                 float* __restrict__ agg) {
    constexpr int CH = D / 4;
    int tid = blockIdx.x * blockDim.x + threadIdx.x;
    if (tid >= EE * CH) return;
    int edge = tid / CH;
    int c = tid - edge * CH;
    int s = src[edge];
    int d = dst[edge];
    float4 v = *reinterpret_cast<const float4*>(feat + (size_t)s * D + c * 4);
    if (LRELU) {
        v.x = v.x > 0.f ? v.x : 0.01f * v.x;
        v.y = v.y > 0.f ? v.y : 0.01f * v.y;
        v.z = v.z > 0.f ? v.z : 0.01f * v.z;
        v.w = v.w > 0.f ? v.w : 0.01f * v.w;
    }
    float* p = agg + (size_t)d * D + c * 4;
    atomicAdd(p + 0, v.x);
    atomicAdd(p + 1, v.y);
    atomicAdd(p + 2, v.z);
    atomicAdd(p + 3, v.w);
}

// ---------------- out[n] += mask_e * ((agg_e[n]/cnt_e[n]) @ W_e + b_e) ----------------
// block = 256 threads, 32 nodes/block. Thread (hg = t&31, ng = t>>5) computes
// 4 nodes (ng, ng+8, ng+16, ng+24) x 4 outputs (hg*4..hg*4+3).
// W staged in LDS in 64-row panels (32 KB), agg tile (32xD) staged scaled by 1/cnt.
template <int D>
__launch_bounds__(256)
__global__ void transform_kernel(const float* __restrict__ agg,
                                 const float* __restrict__ cnt_e,
                                 const float* __restrict__ W_e,
                                 const float* __restrict__ b_e,
                                 float* __restrict__ out) {
    __shared__ float s_W[64 * DH];     // 32 KB panel
    __shared__ float s_agg[32 * D];    // 8 KB (D=64) / 16 KB (D=128)
    __shared__ float s_scale[32];
    __shared__ float s_mask[32];

    const int t = threadIdx.x;
    const int n0 = blockIdx.x * 32;    // NN % 32 == 0 -> no tail guard needed

    if (t < 32) {
        float c = cnt_e[n0 + t];
        s_scale[t] = c > 0.f ? 1.f / c : 0.f;
        s_mask[t]  = c > 0.f ? 1.f : 0.f;
    }
    __syncthreads();
    for (int i = t; i < 32 * D; i += 256) {
        int r = i / D;
        s_agg[i] = agg[(size_t)(n0 + r) * D + (i - r * D)] * s_scale[r];
    }

    const int hg = t & 31;
    const int ng = t >> 5;
    float acc[4][4] = {};

    for (int ph = 0; ph < D / 64; ++ph) {
        __syncthreads();   // prev phase done with s_W; also covers s_agg fill on ph==0
        for (int i = t; i < 64 * DH; i += 256) s_W[i] = W_e[ph * 64 * DH + i];
        __syncthreads();
        const float4* Wv = reinterpret_cast<const float4*>(s_W);
        #pragma unroll
        for (int d4 = 0; d4 < 16; ++d4) {
            float4 a[4];
            #pragma unroll
            for (int i = 0; i < 4; ++i)
                a[i] = *reinterpret_cast<const float4*>(
                    &s_agg[(ng + i * 8) * D + ph * 64 + d4 * 4]);
            #pragma unroll
            for (int j = 0; j < 4; ++j) {
                float4 w = Wv[(d4 * 4 + j) * 32 + hg];
                #pragma unroll
                for (int i = 0; i < 4; ++i) {
                    float aj = (j == 0) ? a[i].x : (j == 1) ? a[i].y
                             : (j == 2) ? a[i].z : a[i].w;
                    acc[i][0] += aj * w.x;
                    acc[i][1] += aj * w.y;
                    acc[i][2] += aj * w.z;
                    acc[i][3] += aj * w.w;
                }
            }
        }
    }

    float4 b = *reinterpret_cast<const float4*>(b_e + hg * 4);
    #pragma unroll
    for (int i = 0; i < 4; ++i) {
        int nl = ng + i * 8;
        float m = s_mask[nl];
        float* op = out + (size_t)(n0 + nl) * DH + hg * 4;
        float4 cur = *reinterpret_cast<const float4*>(op);
        cur.x += m * (acc[i][0] + b.x);
        cur.y += m * (acc[i][1] + b.y);
        cur.z += m * (acc[i][2] + b.z);
        cur.w += m * (acc[i][3] + b.w);
        *reinterpret_cast<float4*>(op) = cur;
    }
}

extern "C" void kernel_launch(void* const* d_in, const int* in_sizes, int n_in,
                              void* d_out, int out_size, void* d_ws, size_t ws_size,
                              hipStream_t stream) {
    const float* x   = (const float*)d_in[0];   // [NN, 64]
    const int* esrc  = (const int*)d_in[1];     // [3, EE]
    const int* edst  = (const int*)d_in[2];     // [3, EE]
    const float* W1  = (const float*)d_in[3];   // [3, 64, 128]
    const float* b1  = (const float*)d_in[4];   // [3, 128]
    const float* W2  = (const float*)d_in[5];   // [3, 128, 128]
    const float* b2  = (const float*)d_in[6];   // [3, 128]
    float* out = (float*)d_out;                 // [NN, 128]

    float* agg = (float*)d_ws;                   // NN*128 floats (used as NN*64 in layer 1)
    float* h   = agg + (size_t)NN * 128;         // NN*128 floats
    float* cnt = h   + (size_t)NN * 128;         // 3*NN floats
    // total ws use: ~104 MB

    // in-degree counts (identical for both layers)
    hipMemsetAsync(cnt, 0, sizeof(float) * NETY * NN, stream);
    count_kernel<<<(NETY * EE + 255) / 256, 256, 0, stream>>>(edst, cnt);

    // ---------------- layer 1 ----------------
    hipMemsetAsync(h, 0, sizeof(float) * (size_t)NN * DH, stream);
    for (int e = 0; e < NETY; ++e) {
        hipMemsetAsync(agg, 0, sizeof(float) * (size_t)NN * 64, stream);
        aggregate_kernel<64, false><<<(EE * 16 + 255) / 256, 256, 0, stream>>>(
            x, esrc + (size_t)e * EE, edst + (size_t)e * EE, agg);
        transform_kernel<64><<<NN / 32, 256, 0, stream>>>(
            agg, cnt + (size_t)e * NN, W1 + (size_t)e * 64 * DH, b1 + (size_t)e * DH, h);
    }

    // ---------------- layer 2 (leaky_relu fused into the gather) ----------------
    hipMemsetAsync(out, 0, sizeof(float) * (size_t)NN * DH, stream);
    for (int e = 0; e < NETY; ++e) {
        hipMemsetAsync(agg, 0, sizeof(float) * (size_t)NN * DH, stream);
        aggregate_kernel<128, true><<<(EE * 32 + 255) / 256, 256, 0, stream>>>(
            h, esrc + (size_t)e * EE, edst + (size_t)e * EE, agg);
        transform_kernel<128><<<NN / 32, 256, 0, stream>>>(
            agg, cnt + (size_t)e * NN, W2 + (size_t)e * DH * DH, b2 + (size_t)e * DH, out);
    }
}

// Round 4
// 653.963 us; speedup vs baseline: 3.1462x; 3.1462x over previous
//
#include <hip/hip_runtime.h>

#define NN 100000
#define NETY 3
#define EE 200000
#define DH 128
#define NBINS (NETY * NN)
#define SCAN_B 1024

// ---------- bf16 helpers ----------
__device__ __forceinline__ float bf2f(unsigned short u) {
    return __uint_as_float(((unsigned int)u) << 16);
}
__device__ __forceinline__ unsigned short f2bf(float f) {
    unsigned int u = __float_as_uint(f);
    unsigned int r = ((u >> 16) & 1u) + 0x7fffu;   // round-to-nearest-even
    return (unsigned short)((u + r) >> 16);
}

// ---------- CSR build: histogram by (etype, dst) ----------
__global__ void hist_kernel(const int* __restrict__ dst, int* __restrict__ cnt) {
    int tid = blockIdx.x * blockDim.x + threadIdx.x;
    if (tid >= NETY * EE) return;
    int e = tid / EE;
    atomicAdd(&cnt[e * NN + dst[tid]], 1);
}

// ---------- exclusive scan over NBINS ints (3 kernels) ----------
__global__ void scan1_kernel(const int* __restrict__ in, int* __restrict__ out,
                             int* __restrict__ bsum, int N) {
    __shared__ int s[256];
    int t = threadIdx.x;
    int base = blockIdx.x * SCAN_B + t * 4;
    int v0 = base + 0 < N ? in[base + 0] : 0;
    int v1 = base + 1 < N ? in[base + 1] : 0;
    int v2 = base + 2 < N ? in[base + 2] : 0;
    int v3 = base + 3 < N ? in[base + 3] : 0;
    int sum = v0 + v1 + v2 + v3;
    s[t] = sum;
    __syncthreads();
    for (int off = 1; off < 256; off <<= 1) {
        int x = (t >= off) ? s[t - off] : 0;
        __syncthreads();
        s[t] += x;
        __syncthreads();
    }
    int excl = s[t] - sum;
    if (base + 0 < N) out[base + 0] = excl;
    excl += v0;
    if (base + 1 < N) out[base + 1] = excl;
    excl += v1;
    if (base + 2 < N) out[base + 2] = excl;
    excl += v2;
    if (base + 3 < N) out[base + 3] = excl;
    if (t == 255) bsum[blockIdx.x] = s[255];
}

__global__ void scan2_kernel(int* __restrict__ bsum, int NB) {
    __shared__ int s[512];
    int t = threadIdx.x;
    int v = (t < NB) ? bsum[t] : 0;
    s[t] = v;
    __syncthreads();
    for (int off = 1; off < 512; off <<= 1) {
        int x = (t >= off) ? s[t - off] : 0;
        __syncthreads();
        s[t] += x;
        __syncthreads();
    }
    if (t < NB) bsum[t] = s[t] - v;   // exclusive
}

__global__ void scan3_kernel(int* __restrict__ out, const int* __restrict__ bsum, int N) {
    int add = bsum[blockIdx.x];
    int base = blockIdx.x * SCAN_B + threadIdx.x * 4;
    if (base + 0 < N) out[base + 0] += add;
    if (base + 1 < N) out[base + 1] += add;
    if (base + 2 < N) out[base + 2] += add;
    if (base + 3 < N) out[base + 3] += add;
}

// ---------- scatter edges into CSR (off becomes END pointers) ----------
__global__ void scatter_kernel(const int* __restrict__ src, const int* __restrict__ dst,
                               int* __restrict__ off, int* __restrict__ sorted) {
    int tid = blockIdx.x * blockDim.x + threadIdx.x;
    if (tid >= NETY * EE) return;
    int e = tid / EE;
    int pos = atomicAdd(&off[e * NN + dst[tid]], 1);
    sorted[pos] = src[tid];
}

// ---------- CSR aggregate, layer 1: mean of x[src] rows (fp32, D=64) ----------
// one wave per dst node; lane l owns column l. Writes mean (0 if no edges).
__global__ void csr_agg64_kernel(const float* __restrict__ x, const int* __restrict__ sorted,
                                 const int* __restrict__ off_e, const int* __restrict__ cnt_e,
                                 float* __restrict__ agg) {
    int node = blockIdx.x * 4 + (threadIdx.x >> 6);
    if (node >= NN) return;
    int lane = threadIdx.x & 63;
    int end = off_e[node];
    int c = cnt_e[node];
    float acc = 0.f;
    for (int i = end - c; i < end; ++i) {
        int s = sorted[i];
        acc += x[(size_t)s * 64 + lane];
    }
    agg[(size_t)node * 64 + lane] = c > 0 ? acc * (1.f / (float)c) : 0.f;
}

// ---------- CSR aggregate, layer 2: mean of leaky_relu(h[src]) (bf16 in, D=128) ----------
// one wave per dst node; lane l owns columns 2l, 2l+1.
__global__ void csr_agg128_kernel(const unsigned short* __restrict__ h,
                                  const int* __restrict__ sorted,
                                  const int* __restrict__ off_e, const int* __restrict__ cnt_e,
                                  float* __restrict__ agg) {
    int node = blockIdx.x * 4 + (threadIdx.x >> 6);
    if (node >= NN) return;
    int lane = threadIdx.x & 63;
    int end = off_e[node];
    int c = cnt_e[node];
    float a0 = 0.f, a1 = 0.f;
    for (int i = end - c; i < end; ++i) {
        int s = sorted[i];
        ushort2 u = *reinterpret_cast<const ushort2*>(h + (size_t)s * DH + lane * 2);
        float f0 = bf2f(u.x), f1 = bf2f(u.y);
        f0 = f0 > 0.f ? f0 : 0.01f * f0;
        f1 = f1 > 0.f ? f1 : 0.01f * f1;
        a0 += f0;
        a1 += f1;
    }
    float inv = c > 0 ? 1.f / (float)c : 0.f;
    *reinterpret_cast<float2*>(agg + (size_t)node * DH + lane * 2) = make_float2(a0 * inv, a1 * inv);
}

// ---------- out(+)= mask_e*(mean_e @ W_e + b_e) ----------
// block=256, 32 nodes/block; thread (hg=t&31, ng=t>>5): 4 nodes x 4 cols register tile.
// agg already holds the mean (pre-scaled); mask only gates the bias-bearing term.
template <int D, bool FIRST, bool BF16OUT>
__launch_bounds__(256)
__global__ void transform_kernel(const float* __restrict__ agg,
                                 const int* __restrict__ cnt_e,
                                 const float* __restrict__ W_e,
                                 const float* __restrict__ b_e,
                                 void* __restrict__ outv) {
    __shared__ float s_W[64 * DH];     // 32 KB panel
    __shared__ float s_agg[32 * D];    // 8/16 KB
    __shared__ float s_mask[32];

    const int t = threadIdx.x;
    const int n0 = blockIdx.x * 32;

    if (t < 32) s_mask[t] = cnt_e[n0 + t] > 0 ? 1.f : 0.f;
    for (int i = t; i < 32 * D; i += 256) s_agg[i] = agg[(size_t)n0 * D + i];

    const int hg = t & 31;
    const int ng = t >> 5;
    float acc[4][4] = {};

    for (int ph = 0; ph < D / 64; ++ph) {
        __syncthreads();   // covers s_agg/s_mask fill (ph==0) and prev phase's s_W use
        for (int i = t; i < 64 * DH; i += 256) s_W[i] = W_e[ph * 64 * DH + i];
        __syncthreads();
        const float4* Wv = reinterpret_cast<const float4*>(s_W);
        #pragma unroll
        for (int d4 = 0; d4 < 16; ++d4) {
            float4 a[4];
            #pragma unroll
            for (int i = 0; i < 4; ++i)
                a[i] = *reinterpret_cast<const float4*>(
                    &s_agg[(ng + i * 8) * D + ph * 64 + d4 * 4]);
            #pragma unroll
            for (int j = 0; j < 4; ++j) {
                float4 w = Wv[(d4 * 4 + j) * 32 + hg];
                #pragma unroll
                for (int i = 0; i < 4; ++i) {
                    float aj = (j == 0) ? a[i].x : (j == 1) ? a[i].y
                             : (j == 2) ? a[i].z : a[i].w;
                    acc[i][0] += aj * w.x;
                    acc[i][1] += aj * w.y;
                    acc[i][2] += aj * w.z;
                    acc[i][3] += aj * w.w;
                }
            }
        }
    }

    float4 b4 = *reinterpret_cast<const float4*>(b_e + hg * 4);
    #pragma unroll
    for (int i = 0; i < 4; ++i) {
        int nl = ng + i * 8;
        float m = s_mask[nl];
        float v0 = m * (acc[i][0] + b4.x);
        float v1 = m * (acc[i][1] + b4.y);
        float v2 = m * (acc[i][2] + b4.z);
        float v3 = m * (acc[i][3] + b4.w);
        if constexpr (BF16OUT) {
            unsigned short* op = (unsigned short*)outv + (size_t)(n0 + nl) * DH + hg * 4;
            if constexpr (!FIRST) {
                ushort4 old = *reinterpret_cast<const ushort4*>(op);
                v0 += bf2f(old.x); v1 += bf2f(old.y); v2 += bf2f(old.z); v3 += bf2f(old.w);
            }
            ushort4 o;
            o.x = f2bf(v0); o.y = f2bf(v1); o.z = f2bf(v2); o.w = f2bf(v3);
            *reinterpret_cast<ushort4*>(op) = o;
        } else {
            float* op = (float*)outv + (size_t)(n0 + nl) * DH + hg * 4;
            float4 o = make_float4(v0, v1, v2, v3);
            if constexpr (!FIRST) {
                float4 old = *reinterpret_cast<const float4*>(op);
                o.x += old.x; o.y += old.y; o.z += old.z; o.w += old.w;
            }
            *reinterpret_cast<float4*>(op) = o;
        }
    }
}

extern "C" void kernel_launch(void* const* d_in, const int* in_sizes, int n_in,
                              void* d_out, int out_size, void* d_ws, size_t ws_size,
                              hipStream_t stream) {
    const float* x   = (const float*)d_in[0];   // [NN, 64]
    const int* esrc  = (const int*)d_in[1];     // [3, EE]
    const int* edst  = (const int*)d_in[2];     // [3, EE]
    const float* W1  = (const float*)d_in[3];   // [3, 64, 128]
    const float* b1  = (const float*)d_in[4];   // [3, 128]
    const float* W2  = (const float*)d_in[5];   // [3, 128, 128]
    const float* b2  = (const float*)d_in[6];   // [3, 128]
    float* out = (float*)d_out;                 // [NN, 128] fp32

    // workspace layout (81.6 MB total)
    int* cnt    = (int*)d_ws;                   // [3*NN]
    int* off    = cnt + NBINS;                  // [3*NN] -> end-pointers after scatter
    int* sorted = off + NBINS;                  // [3*EE]
    int* bsum   = sorted + NETY * EE;           // [<=512]
    float* agg  = (float*)(bsum + 512);         // [NN*128] fp32 (layer1 uses NN*64)
    unsigned short* h = (unsigned short*)(agg + (size_t)NN * DH);  // [NN*128] bf16

    const int NB = (NBINS + SCAN_B - 1) / SCAN_B;   // 293

    // ---- CSR build (shared by both layers) ----
    hipMemsetAsync(cnt, 0, sizeof(int) * NBINS, stream);
    hist_kernel<<<(NETY * EE + 255) / 256, 256, 0, stream>>>(edst, cnt);
    scan1_kernel<<<NB, 256, 0, stream>>>(cnt, off, bsum, NBINS);
    scan2_kernel<<<1, 512, 0, stream>>>(bsum, NB);
    scan3_kernel<<<NB, 256, 0, stream>>>(off, bsum, NBINS);
    scatter_kernel<<<(NETY * EE + 255) / 256, 256, 0, stream>>>(esrc, edst, off, sorted);

    // ---- layer 1: agg_e = mean_e(x) ; h (+)= mask*(agg_e @ W1_e + b1_e), bf16 ----
    for (int e = 0; e < NETY; ++e) {
        csr_agg64_kernel<<<NN / 4, 256, 0, stream>>>(
            x, sorted, off + e * NN, cnt + e * NN, agg);
        if (e == 0)
            transform_kernel<64, true, true><<<NN / 32, 256, 0, stream>>>(
                agg, cnt + e * NN, W1 + (size_t)e * 64 * DH, b1 + (size_t)e * DH, h);
        else
            transform_kernel<64, false, true><<<NN / 32, 256, 0, stream>>>(
                agg, cnt + e * NN, W1 + (size_t)e * 64 * DH, b1 + (size_t)e * DH, h);
    }

    // ---- layer 2: agg_e = mean_e(leaky_relu(h)) ; out (+)= mask*(agg_e @ W2_e + b2_e) ----
    for (int e = 0; e < NETY; ++e) {
        csr_agg128_kernel<<<NN / 4, 256, 0, stream>>>(
            h, sorted, off + e * NN, cnt + e * NN, agg);
        if (e == 0)
            transform_kernel<128, true, false><<<NN / 32, 256, 0, stream>>>(
                agg, cnt + e * NN, W2 + (size_t)e * DH * DH, b2 + (size_t)e * DH, out);
        else
            transform_kernel<128, false, false><<<NN / 32, 256, 0, stream>>>(
                agg, cnt + e * NN, W2 + (size_t)e * DH * DH, b2 + (size_t)e * DH, out);
    }
}